// Round 5
// baseline (949.818 us; speedup 1.0000x reference)
//
#include <hip/hip_runtime.h>
#include <math.h>

#define NPTS 8192
#define DIM 32
#define TILE 128
#define NT (NPTS / TILE)              // 64 tiles per side
#define NTP (NT * (NT + 1) / 2)       // 2080 upper-tri tile pairs
#define NBINS 4096
#define BIN_SCALE 20.0f               // bins per unit d^2 -> covers d^2 in [0, 204.8]
#define NR 16
#define MAXP 512

// ---------------- kernel 0: squared norms ----------------
__global__ void k_sq(const float* __restrict__ pts, float* __restrict__ sq) {
    int i = blockIdx.x * blockDim.x + threadIdx.x;
    if (i >= NPTS) return;
    const float4* r = (const float4*)(pts + (size_t)i * DIM);
    float s = 0.f;
#pragma unroll
    for (int q = 0; q < DIM / 4; ++q) {
        float4 v = r[q];
        s += v.x * v.x + v.y * v.y + v.z * v.z + v.w * v.w;
    }
    sq[i] = s;
}

// ---------------- kernel 1: pairwise d^2 histogram ----------------
// 1024 threads = 32x32 grid; each thread owns 4 rows x 4 strided cols.
// 16 named-scalar accs -> register demand ~64 VGPRs, 2x headroom under
// the 128 tier pinned by amdgpu_waves_per_eu(4,4). Rounds 1-4 showed the
// allocator picks an occupancy tier (64/128) and spills overflow to
// scratch (~640MB deterministic writes); this config cannot spill.

#define FMA4(C, A, B) \
    C = fmaf(A.x, B.x, C); C = fmaf(A.y, B.y, C); \
    C = fmaf(A.z, B.z, C); C = fmaf(A.w, B.w, C);

#define SEGBLK(S) { \
    const int seg = S; \
    const float4 bv0 = Bt[seg][(tx) ^ seg]; \
    const float4 bv1 = Bt[seg][(32 + tx) ^ seg]; \
    const float4 bv2 = Bt[seg][(64 + tx) ^ seg]; \
    const float4 bv3 = Bt[seg][(96 + tx) ^ seg]; \
    const float4 a0 = At[seg][((ty << 2) + 0) ^ seg]; \
    const float4 a1 = At[seg][((ty << 2) + 1) ^ seg]; \
    const float4 a2 = At[seg][((ty << 2) + 2) ^ seg]; \
    const float4 a3 = At[seg][((ty << 2) + 3) ^ seg]; \
    FMA4(c00, a0, bv0) FMA4(c01, a0, bv1) FMA4(c02, a0, bv2) FMA4(c03, a0, bv3) \
    FMA4(c10, a1, bv0) FMA4(c11, a1, bv1) FMA4(c12, a1, bv2) FMA4(c13, a1, bv3) \
    FMA4(c20, a2, bv0) FMA4(c21, a2, bv1) FMA4(c22, a2, bv2) FMA4(c23, a2, bv3) \
    FMA4(c30, a3, bv0) FMA4(c31, a3, bv1) FMA4(c32, a3, bv2) FMA4(c33, a3, bv3) }

#define EPI(m, n) { \
    const float d2 = fmaf(-2.f, c##m##n, sA##m + sB##n); \
    const int bin = (int)fminf(fmaxf(d2, 0.f) * BIN_SCALE, (float)(NBINS - 1)); \
    if (!diag || (((ty << 2) + m) < (n * 32 + tx))) atomicAdd(&hist[bin], 1u); }

__global__ __launch_bounds__(1024)
__attribute__((amdgpu_waves_per_eu(4, 4)))
void k_hist(const float4* __restrict__ p4, const float* __restrict__ sq,
            unsigned* __restrict__ parts) {
    __shared__ unsigned hist[NBINS];          // 16 KB
    __shared__ float4 At[8][TILE];            // 16 KB  (seg-major, cols XOR seg)
    __shared__ float4 Bt[8][TILE];            // 16 KB
    const int tid = threadIdx.x;
    const int tx = tid & 31, ty = tid >> 5;   // 32x32 thread grid
    for (int b = tid; b < NBINS; b += 1024) hist[b] = 0u;
    const int P = gridDim.x;

    for (int tp = blockIdx.x; tp < NTP; tp += P) {
        // decode upper-triangular tile pair (ti <= tj)
        int ti = 0, rr = tp;
        while (rr >= NT - ti) { rr -= NT - ti; ++ti; }
        const int tj = ti + rr;

        __syncthreads();   // previous iteration's reads of At/Bt done
        // stage tiles: one A + one B float4 per thread, perfectly coalesced;
        // LDS column swizzled by ^seg
        {
            const int seg = tid & 7;          // which 4 coords
            const int p = tid >> 3;           // point within tile
            const int sp = p ^ seg;
            At[seg][sp] = p4[(size_t)ti * 1024 + tid];
            Bt[seg][sp] = p4[(size_t)tj * 1024 + tid];
        }
        __syncthreads();

        float c00 = 0.f, c01 = 0.f, c02 = 0.f, c03 = 0.f;
        float c10 = 0.f, c11 = 0.f, c12 = 0.f, c13 = 0.f;
        float c20 = 0.f, c21 = 0.f, c22 = 0.f, c23 = 0.f;
        float c30 = 0.f, c31 = 0.f, c32 = 0.f, c33 = 0.f;

        SEGBLK(0) SEGBLK(1) SEGBLK(2) SEGBLK(3)
        SEGBLK(4) SEGBLK(5) SEGBLK(6) SEGBLK(7)

        const float sA0 = sq[ti * TILE + (ty << 2) + 0];
        const float sA1 = sq[ti * TILE + (ty << 2) + 1];
        const float sA2 = sq[ti * TILE + (ty << 2) + 2];
        const float sA3 = sq[ti * TILE + (ty << 2) + 3];
        const float sB0 = sq[tj * TILE + 0 * 32 + tx];
        const float sB1 = sq[tj * TILE + 1 * 32 + tx];
        const float sB2 = sq[tj * TILE + 2 * 32 + tx];
        const float sB3 = sq[tj * TILE + 3 * 32 + tx];

        const bool diag = (ti == tj);
        EPI(0,0) EPI(0,1) EPI(0,2) EPI(0,3)
        EPI(1,0) EPI(1,1) EPI(1,2) EPI(1,3)
        EPI(2,0) EPI(2,1) EPI(2,2) EPI(2,3)
        EPI(3,0) EPI(3,1) EPI(3,2) EPI(3,3)
    }

    __syncthreads();
    unsigned* my = parts + (size_t)blockIdx.x * NBINS;
    for (int b = tid; b < NBINS; b += 1024) my[b] = hist[b];
}

// ---------------- kernel 2: reduce partials, sigmoid sums ----------------
__global__ void k_sums(const unsigned* __restrict__ parts, int P,
                       const float* __restrict__ rvals, double* __restrict__ sums) {
    const int b = blockIdx.x * 256 + threadIdx.x;
    unsigned long long c;
    {
        unsigned c8[8];
#pragma unroll
        for (int u = 0; u < 8; ++u) c8[u] = 0u;
        int p = 0;
        for (; p + 8 <= P; p += 8) {          // 8 independent loads in flight
#pragma unroll
            for (int u = 0; u < 8; ++u)
                c8[u] += parts[(size_t)(p + u) * NBINS + b];
        }
        for (; p < P; ++p) c8[0] += parts[(size_t)p * NBINS + b];
        unsigned long long t = 0;
#pragma unroll
        for (int u = 0; u < 8; ++u) t += c8[u];
        c = t;
    }

    double local[NR + 1];
#pragma unroll
    for (int t = 0; t < NR; ++t) local[t] = 0.0;
    local[NR] = (double)c;   // pair count

    if (c) {
        const double d = sqrt(((double)b + 0.5) / (double)BIN_SCALE);
#pragma unroll
        for (int t = 0; t < NR; ++t) {
            const double x = 10.0 * ((double)rvals[t] - d);
            double s;
            if (x >= 0.0) s = 1.0 / (1.0 + exp(-x));
            else          { const double e = exp(x); s = e / (1.0 + e); }
            local[t] = (double)c * s;
        }
    }

    // wave(64) reduction, then one atomic per wave per value
#pragma unroll
    for (int off = 32; off > 0; off >>= 1) {
#pragma unroll
        for (int t = 0; t <= NR; ++t)
            local[t] += __shfl_down(local[t], off);
    }
    if ((threadIdx.x & 63) == 0) {
#pragma unroll
        for (int t = 0; t <= NR; ++t) atomicAdd(&sums[t], local[t]);
    }
}

// ---------------- kernel 3: log-log regression ----------------
__global__ void k_fit(const double* __restrict__ sums, const float* __restrict__ rvals,
                      float* __restrict__ out) {
    const double cnt = sums[NR];
    double Sx = 0, Sy = 0, Sxx = 0, Sxy = 0;
#pragma unroll
    for (int t = 0; t < NR; ++t) {
        const double x = log((double)rvals[t]);
        const double y = log(sums[t] / cnt);
        Sx += x; Sy += y; Sxx += x * x; Sxy += x * y;
    }
    const double R = (double)NR;
    const double slope = (R * Sxy - Sx * Sy) / (R * Sxx - Sx * Sx);
    out[0] = (float)(-slope);
}

extern "C" void kernel_launch(void* const* d_in, const int* in_sizes, int n_in,
                              void* d_out, int out_size, void* d_ws, size_t ws_size,
                              hipStream_t stream) {
    const float* pts = (const float*)d_in[0];
    const float* rv  = (const float*)d_in[1];
    float* out = (float*)d_out;
    char* ws = (char*)d_ws;

    float* sq = (float*)ws;                        // 32 KB
    const size_t off_parts = 32768;
    size_t avail = (ws_size > off_parts + 1024) ? (ws_size - off_parts - 1024) : 0;
    int P = (int)(avail / ((size_t)NBINS * sizeof(unsigned)));
    if (P > MAXP) P = MAXP;
    if (P < 1) P = 1;
    unsigned* parts = (unsigned*)(ws + off_parts);
    double* sums = (double*)(ws + off_parts + (size_t)P * NBINS * sizeof(unsigned));

    hipMemsetAsync(sums, 0, (NR + 1) * sizeof(double), stream);
    k_sq<<<NPTS / 256, 256, 0, stream>>>(pts, sq);
    k_hist<<<P, 1024, 0, stream>>>((const float4*)pts, sq, parts);
    k_sums<<<NBINS / 256, 256, 0, stream>>>(parts, P, rv, sums);
    k_fit<<<1, 1, 0, stream>>>(sums, rv, out);
}

// Round 6
// 90.112 us; speedup vs baseline: 10.5404x; 10.5404x over previous
//
#include <hip/hip_runtime.h>
#include <math.h>

#define NPTS 8192
#define DIM 32
#define TILE 128
#define NT (NPTS / TILE)              // 64 tiles per side
#define NTP (NT * (NT + 1) / 2)       // 2080 upper-tri tile pairs
#define NBINS 4096
#define BIN_SCALE 20.0f               // bins per unit d^2
#define NR 16
#define MAXP 512
#define LROW 40                       // shorts per LDS panel row (80 B padded)

using bf16x8 = __attribute__((ext_vector_type(8))) short;
using f32x4  = __attribute__((ext_vector_type(4))) float;

__device__ __forceinline__ unsigned short f2bf(float f) {
    unsigned u = __float_as_uint(f);
    return (unsigned short)((u + 0x7fffu + ((u >> 16) & 1u)) >> 16);
}

// ---------------- kernel 0: fp32 -> bf16 points + exact fp32 norms ----------
// 2 threads per point; each handles 16 coords, shfl_xor combines norms.
__global__ void k_prep(const float* __restrict__ pts, unsigned* __restrict__ bp,
                       float* __restrict__ sq) {
    const int t = blockIdx.x * 256 + threadIdx.x;   // 0..16383
    const int p = t >> 1, h = t & 1;
    const float4* src = (const float4*)(pts + (size_t)p * DIM + h * 16);
    const float4 v0 = src[0], v1 = src[1], v2 = src[2], v3 = src[3];
    float s = v0.x * v0.x + v0.y * v0.y + v0.z * v0.z + v0.w * v0.w
            + v1.x * v1.x + v1.y * v1.y + v1.z * v1.z + v1.w * v1.w
            + v2.x * v2.x + v2.y * v2.y + v2.z * v2.z + v2.w * v2.w
            + v3.x * v3.x + v3.y * v3.y + v3.z * v3.z + v3.w * v3.w;
    s += __shfl_xor(s, 1);
    if (!h) sq[p] = s;
    unsigned* dst = bp + (size_t)p * 16 + h * 8;    // 8 uints = 16 bf16
    dst[0] = (unsigned)f2bf(v0.x) | ((unsigned)f2bf(v0.y) << 16);
    dst[1] = (unsigned)f2bf(v0.z) | ((unsigned)f2bf(v0.w) << 16);
    dst[2] = (unsigned)f2bf(v1.x) | ((unsigned)f2bf(v1.y) << 16);
    dst[3] = (unsigned)f2bf(v1.z) | ((unsigned)f2bf(v1.w) << 16);
    dst[4] = (unsigned)f2bf(v2.x) | ((unsigned)f2bf(v2.y) << 16);
    dst[5] = (unsigned)f2bf(v2.z) | ((unsigned)f2bf(v2.w) << 16);
    dst[6] = (unsigned)f2bf(v3.x) | ((unsigned)f2bf(v3.y) << 16);
    dst[7] = (unsigned)f2bf(v3.z) | ((unsigned)f2bf(v3.w) << 16);
}

// ---------------- kernel 1: MFMA gram + d^2 histogram ----------------------
// DIM=32 == K of mfma_f32_16x16x32_bf16: ONE MFMA = one full 16x16 block of
// the gram matrix; acc (4 VGPRs) is consumed immediately -> nothing for
// regalloc to spill (r1-r5 all died on accumulator-array scratch traffic).
// 256 thr = 4 waves; wave w owns tile-rows {2w,2w+1} x 8 tile-cols of the
// 128x128 block tile. Panels: bf16, 80B-padded rows; staging writes are
// contiguous; ds_read_b128 fragment reads hit the structural bank minimum.

#define EPI1(ACC, SA, GROW) { \
    const float d2_ = fmaf(-2.f, ACC, (SA) + sb); \
    const int bin_ = (int)fminf(fmaxf(d2_, 0.f) * BIN_SCALE, (float)(NBINS - 1)); \
    if (!diag || ((GROW) < gcol)) atomicAdd(&hist[bin_], 1u); }

__global__ __launch_bounds__(256)
void k_hist(const uint4* __restrict__ bp4, const float* __restrict__ sq,
            unsigned* __restrict__ parts) {
    __shared__ unsigned hist[NBINS];                 // 16 KB
    __shared__ unsigned short Ab[TILE * LROW];       // 10 KB
    __shared__ unsigned short Bb[TILE * LROW];       // 10 KB
    __shared__ float sqa[TILE], sqb[TILE];           // 1 KB
    const int tid = threadIdx.x;
    const int lane = tid & 63, w = tid >> 6;
    const int l15 = lane & 15, lc = lane >> 4;       // col-in-tile, k-chunk
    for (int b = tid; b < NBINS; b += 256) hist[b] = 0u;
    const int P = gridDim.x;

    for (int tp = blockIdx.x; tp < NTP; tp += P) {
        int ti = 0, rr = tp;
        while (rr >= NT - ti) { rr -= NT - ti; ++ti; }
        const int tj = ti + rr;

        __syncthreads();   // prior iteration's reads + atomics done
        // stage panels: 512 uint4 each; global reads contiguous,
        // LDS writes contiguous-per-row (80B padded rows)
#pragma unroll
        for (int q = 0; q < 2; ++q) {
            const int g = tid + q * 256;             // 0..511
            const int p = g >> 2, c = g & 3;
            *(uint4*)&Ab[p * LROW + c * 8] = bp4[(size_t)ti * 512 + g];
            *(uint4*)&Bb[p * LROW + c * 8] = bp4[(size_t)tj * 512 + g];
        }
        if (tid < TILE) sqa[tid] = sq[ti * TILE + tid];
        else if (tid < 2 * TILE) sqb[tid - TILE] = sq[tj * TILE + (tid - TILE)];
        __syncthreads();

        const int r0 = (2 * w) * 16, r1 = r0 + 16;   // this wave's tile-rows
        const bf16x8 a0 = *(const bf16x8*)&Ab[(r0 + l15) * LROW + lc * 8];
        const bf16x8 a1 = *(const bf16x8*)&Ab[(r1 + l15) * LROW + lc * 8];
        const float sa00 = sqa[r0 + lc * 4 + 0];
        const float sa01 = sqa[r0 + lc * 4 + 1];
        const float sa02 = sqa[r0 + lc * 4 + 2];
        const float sa03 = sqa[r0 + lc * 4 + 3];
        const float sa10 = sqa[r1 + lc * 4 + 0];
        const float sa11 = sqa[r1 + lc * 4 + 1];
        const float sa12 = sqa[r1 + lc * 4 + 2];
        const float sa13 = sqa[r1 + lc * 4 + 3];
        const bool diag = (ti == tj);
        const int g0 = ti * TILE + r0 + lc * 4;      // + j  = global row
        const int g1 = ti * TILE + r1 + lc * 4;

#pragma unroll
        for (int tc = 0; tc < 8; ++tc) {
            const bf16x8 bf = *(const bf16x8*)&Bb[(tc * 16 + l15) * LROW + lc * 8];
            const f32x4 z = {0.f, 0.f, 0.f, 0.f};
            const f32x4 d0 = __builtin_amdgcn_mfma_f32_16x16x32_bf16(a0, bf, z, 0, 0, 0);
            const f32x4 d1 = __builtin_amdgcn_mfma_f32_16x16x32_bf16(a1, bf, z, 0, 0, 0);
            const float sb = sqb[tc * 16 + l15];
            const int gcol = tj * TILE + tc * 16 + l15;
            EPI1(d0[0], sa00, g0 + 0) EPI1(d0[1], sa01, g0 + 1)
            EPI1(d0[2], sa02, g0 + 2) EPI1(d0[3], sa03, g0 + 3)
            EPI1(d1[0], sa10, g1 + 0) EPI1(d1[1], sa11, g1 + 1)
            EPI1(d1[2], sa12, g1 + 2) EPI1(d1[3], sa13, g1 + 3)
        }
    }

    __syncthreads();
    unsigned* my = parts + (size_t)blockIdx.x * NBINS;
    for (int b = tid; b < NBINS; b += 256) my[b] = hist[b];
}

// ---------------- kernel 2: reduce partials, sigmoid sums ----------------
__global__ void k_sums(const unsigned* __restrict__ parts, int P,
                       const float* __restrict__ rvals, double* __restrict__ sums) {
    const int b = blockIdx.x * 256 + threadIdx.x;
    unsigned long long c;
    {
        unsigned c8[8];
#pragma unroll
        for (int u = 0; u < 8; ++u) c8[u] = 0u;
        int p = 0;
        for (; p + 8 <= P; p += 8) {
#pragma unroll
            for (int u = 0; u < 8; ++u)
                c8[u] += parts[(size_t)(p + u) * NBINS + b];
        }
        for (; p < P; ++p) c8[0] += parts[(size_t)p * NBINS + b];
        unsigned long long t = 0;
#pragma unroll
        for (int u = 0; u < 8; ++u) t += c8[u];
        c = t;
    }

    double local[NR + 1];
#pragma unroll
    for (int t = 0; t < NR; ++t) local[t] = 0.0;
    local[NR] = (double)c;

    if (c) {
        const double d = sqrt(((double)b + 0.5) / (double)BIN_SCALE);
#pragma unroll
        for (int t = 0; t < NR; ++t) {
            const double x = 10.0 * ((double)rvals[t] - d);
            double s;
            if (x >= 0.0) s = 1.0 / (1.0 + exp(-x));
            else          { const double e = exp(x); s = e / (1.0 + e); }
            local[t] = (double)c * s;
        }
    }

#pragma unroll
    for (int off = 32; off > 0; off >>= 1) {
#pragma unroll
        for (int t = 0; t <= NR; ++t)
            local[t] += __shfl_down(local[t], off);
    }
    if ((threadIdx.x & 63) == 0) {
#pragma unroll
        for (int t = 0; t <= NR; ++t) atomicAdd(&sums[t], local[t]);
    }
}

// ---------------- kernel 3: log-log regression ----------------
__global__ void k_fit(const double* __restrict__ sums, const float* __restrict__ rvals,
                      float* __restrict__ out) {
    const double cnt = sums[NR];
    double Sx = 0, Sy = 0, Sxx = 0, Sxy = 0;
#pragma unroll
    for (int t = 0; t < NR; ++t) {
        const double x = log((double)rvals[t]);
        const double y = log(sums[t] / cnt);
        Sx += x; Sy += y; Sxx += x * x; Sxy += x * y;
    }
    const double R = (double)NR;
    const double slope = (R * Sxy - Sx * Sy) / (R * Sxx - Sx * Sx);
    out[0] = (float)(-slope);
}

extern "C" void kernel_launch(void* const* d_in, const int* in_sizes, int n_in,
                              void* d_out, int out_size, void* d_ws, size_t ws_size,
                              hipStream_t stream) {
    const float* pts = (const float*)d_in[0];
    const float* rv  = (const float*)d_in[1];
    float* out = (float*)d_out;
    char* ws = (char*)d_ws;

    unsigned* bp = (unsigned*)ws;                  // 512 KB bf16 points
    float* sq = (float*)(ws + 524288);             // 32 KB norms
    const size_t off_parts = 524288 + 32768;       // 557056
    size_t avail = (ws_size > off_parts + 1024) ? (ws_size - off_parts - 1024) : 0;
    int P = (int)(avail / ((size_t)NBINS * sizeof(unsigned)));
    if (P > MAXP) P = MAXP;
    if (P < 1) P = 1;
    unsigned* parts = (unsigned*)(ws + off_parts);
    double* sums = (double*)(ws + off_parts + (size_t)P * NBINS * sizeof(unsigned));

    hipMemsetAsync(sums, 0, (NR + 1) * sizeof(double), stream);
    k_prep<<<64, 256, 0, stream>>>(pts, bp, sq);
    k_hist<<<P, 256, 0, stream>>>((const uint4*)bp, sq, parts);
    k_sums<<<NBINS / 256, 256, 0, stream>>>(parts, P, rv, sums);
    k_fit<<<1, 1, 0, stream>>>(sums, rv, out);
}

// Round 7
// 69.577 us; speedup vs baseline: 13.6513x; 1.2951x over previous
//
#include <hip/hip_runtime.h>
#include <math.h>

#define NPTS 8192
#define DIM 32
#define TILE 128
#define NT (NPTS / TILE)              // 64 tiles per side
#define NTP (NT * (NT + 1) / 2)       // 2080 upper-tri tile pairs
#define NBINS 4096
#define BIN_SCALE 20.0f               // bins per unit d^2
#define NR 16
#define NBLK 512                      // k_hist persistent grid
#define LROW 40                       // shorts per LDS panel row (80 B padded)

using bf16x8 = __attribute__((ext_vector_type(8))) short;
using f32x4  = __attribute__((ext_vector_type(4))) float;

__device__ __forceinline__ unsigned short f2bf(float f) {
    unsigned u = __float_as_uint(f);
    return (unsigned short)((u + 0x7fffu + ((u >> 16) & 1u)) >> 16);
}

// ---------------- kernel 0: fp32 -> bf16 points + exact fp32 norms ----------
__global__ void k_prep(const float* __restrict__ pts, unsigned* __restrict__ bp,
                       float* __restrict__ sq) {
    const int t = blockIdx.x * 256 + threadIdx.x;   // 0..16383
    const int p = t >> 1, h = t & 1;
    const float4* src = (const float4*)(pts + (size_t)p * DIM + h * 16);
    const float4 v0 = src[0], v1 = src[1], v2 = src[2], v3 = src[3];
    float s = v0.x * v0.x + v0.y * v0.y + v0.z * v0.z + v0.w * v0.w
            + v1.x * v1.x + v1.y * v1.y + v1.z * v1.z + v1.w * v1.w
            + v2.x * v2.x + v2.y * v2.y + v2.z * v2.z + v2.w * v2.w
            + v3.x * v3.x + v3.y * v3.y + v3.z * v3.z + v3.w * v3.w;
    s += __shfl_xor(s, 1);
    if (!h) sq[p] = s;
    unsigned* dst = bp + (size_t)p * 16 + h * 8;    // 8 uints = 16 bf16
    dst[0] = (unsigned)f2bf(v0.x) | ((unsigned)f2bf(v0.y) << 16);
    dst[1] = (unsigned)f2bf(v0.z) | ((unsigned)f2bf(v0.w) << 16);
    dst[2] = (unsigned)f2bf(v1.x) | ((unsigned)f2bf(v1.y) << 16);
    dst[3] = (unsigned)f2bf(v1.z) | ((unsigned)f2bf(v1.w) << 16);
    dst[4] = (unsigned)f2bf(v2.x) | ((unsigned)f2bf(v2.y) << 16);
    dst[5] = (unsigned)f2bf(v2.z) | ((unsigned)f2bf(v2.w) << 16);
    dst[6] = (unsigned)f2bf(v3.x) | ((unsigned)f2bf(v3.y) << 16);
    dst[7] = (unsigned)f2bf(v3.z) | ((unsigned)f2bf(v3.w) << 16);
}

// ---------------- kernel 1: MFMA gram + d^2 histogram ----------------------
// DIM=32 == K of mfma_f32_16x16x32_bf16: one MFMA = one full 16x16 gram
// block; acc (4 VGPRs) is consumed immediately -> nothing to spill.
// Flush: global atomics straight into cnt[4096] (u32, deterministic);
// no partials array, no reduction kernel (r6: k_sums was 45us latency-bound).

#define EPI1(ACC, SA, GROW) { \
    const float d2_ = fmaf(-2.f, ACC, (SA) + sb); \
    const int bin_ = (int)fminf(fmaxf(d2_, 0.f) * BIN_SCALE, (float)(NBINS - 1)); \
    if (!diag || ((GROW) < gcol)) atomicAdd(&hist[bin_], 1u); }

__global__ __launch_bounds__(256)
void k_hist(const uint4* __restrict__ bp4, const float* __restrict__ sq,
            unsigned* __restrict__ cnt) {
    __shared__ unsigned hist[NBINS];                 // 16 KB
    __shared__ unsigned short Ab[TILE * LROW];       // 10 KB
    __shared__ unsigned short Bb[TILE * LROW];       // 10 KB
    __shared__ float sqa[TILE], sqb[TILE];           // 1 KB
    const int tid = threadIdx.x;
    const int lane = tid & 63, w = tid >> 6;
    const int l15 = lane & 15, lc = lane >> 4;       // col-in-tile, k-chunk
    for (int b = tid; b < NBINS; b += 256) hist[b] = 0u;
    const int P = gridDim.x;

    for (int tp = blockIdx.x; tp < NTP; tp += P) {
        int ti = 0, rr = tp;
        while (rr >= NT - ti) { rr -= NT - ti; ++ti; }
        const int tj = ti + rr;

        __syncthreads();   // prior iteration's reads + atomics done
#pragma unroll
        for (int q = 0; q < 2; ++q) {
            const int g = tid + q * 256;             // 0..511
            const int p = g >> 2, c = g & 3;
            *(uint4*)&Ab[p * LROW + c * 8] = bp4[(size_t)ti * 512 + g];
            *(uint4*)&Bb[p * LROW + c * 8] = bp4[(size_t)tj * 512 + g];
        }
        if (tid < TILE) sqa[tid] = sq[ti * TILE + tid];
        else if (tid < 2 * TILE) sqb[tid - TILE] = sq[tj * TILE + (tid - TILE)];
        __syncthreads();

        const int r0 = (2 * w) * 16, r1 = r0 + 16;   // this wave's tile-rows
        const bf16x8 a0 = *(const bf16x8*)&Ab[(r0 + l15) * LROW + lc * 8];
        const bf16x8 a1 = *(const bf16x8*)&Ab[(r1 + l15) * LROW + lc * 8];
        const float sa00 = sqa[r0 + lc * 4 + 0];
        const float sa01 = sqa[r0 + lc * 4 + 1];
        const float sa02 = sqa[r0 + lc * 4 + 2];
        const float sa03 = sqa[r0 + lc * 4 + 3];
        const float sa10 = sqa[r1 + lc * 4 + 0];
        const float sa11 = sqa[r1 + lc * 4 + 1];
        const float sa12 = sqa[r1 + lc * 4 + 2];
        const float sa13 = sqa[r1 + lc * 4 + 3];
        const bool diag = (ti == tj);
        const int g0 = ti * TILE + r0 + lc * 4;      // + j  = global row
        const int g1 = ti * TILE + r1 + lc * 4;

#pragma unroll
        for (int tc = 0; tc < 8; ++tc) {
            const bf16x8 bf = *(const bf16x8*)&Bb[(tc * 16 + l15) * LROW + lc * 8];
            const f32x4 z = {0.f, 0.f, 0.f, 0.f};
            const f32x4 d0 = __builtin_amdgcn_mfma_f32_16x16x32_bf16(a0, bf, z, 0, 0, 0);
            const f32x4 d1 = __builtin_amdgcn_mfma_f32_16x16x32_bf16(a1, bf, z, 0, 0, 0);
            const float sb = sqb[tc * 16 + l15];
            const int gcol = tj * TILE + tc * 16 + l15;
            EPI1(d0[0], sa00, g0 + 0) EPI1(d0[1], sa01, g0 + 1)
            EPI1(d0[2], sa02, g0 + 2) EPI1(d0[3], sa03, g0 + 3)
            EPI1(d1[0], sa10, g1 + 0) EPI1(d1[1], sa11, g1 + 1)
            EPI1(d1[2], sa12, g1 + 2) EPI1(d1[3], sa13, g1 + 3)
        }
    }

    __syncthreads();
    for (int b = tid; b < NBINS; b += 256) {
        const unsigned h = hist[b];
        if (h) atomicAdd(&cnt[b], h);                // device-scope, deterministic
    }
}

// ---------------- kernel 2: sigmoid sums from global histogram ------------
__global__ void k_sig(const unsigned* __restrict__ cnt,
                      const float* __restrict__ rvals, double* __restrict__ sums) {
    const int b = blockIdx.x * 256 + threadIdx.x;
    const unsigned c = cnt[b];

    double local[NR + 1];
#pragma unroll
    for (int t = 0; t < NR; ++t) local[t] = 0.0;
    local[NR] = (double)c;

    if (c) {
        const double d = sqrt(((double)b + 0.5) / (double)BIN_SCALE);
#pragma unroll
        for (int t = 0; t < NR; ++t) {
            const double x = 10.0 * ((double)rvals[t] - d);
            double s;
            if (x >= 0.0) s = 1.0 / (1.0 + exp(-x));
            else          { const double e = exp(x); s = e / (1.0 + e); }
            local[t] = (double)c * s;
        }
    }

#pragma unroll
    for (int off = 32; off > 0; off >>= 1) {
#pragma unroll
        for (int t = 0; t <= NR; ++t)
            local[t] += __shfl_down(local[t], off);
    }
    if ((threadIdx.x & 63) == 0) {
#pragma unroll
        for (int t = 0; t <= NR; ++t) atomicAdd(&sums[t], local[t]);
    }
}

// ---------------- kernel 3: log-log regression ----------------
__global__ void k_fit(const double* __restrict__ sums, const float* __restrict__ rvals,
                      float* __restrict__ out) {
    const double cnt = sums[NR];
    double Sx = 0, Sy = 0, Sxx = 0, Sxy = 0;
#pragma unroll
    for (int t = 0; t < NR; ++t) {
        const double x = log((double)rvals[t]);
        const double y = log(sums[t] / cnt);
        Sx += x; Sy += y; Sxx += x * x; Sxy += x * y;
    }
    const double R = (double)NR;
    const double slope = (R * Sxy - Sx * Sy) / (R * Sxx - Sx * Sx);
    out[0] = (float)(-slope);
}

extern "C" void kernel_launch(void* const* d_in, const int* in_sizes, int n_in,
                              void* d_out, int out_size, void* d_ws, size_t ws_size,
                              hipStream_t stream) {
    const float* pts = (const float*)d_in[0];
    const float* rv  = (const float*)d_in[1];
    float* out = (float*)d_out;
    char* ws = (char*)d_ws;

    unsigned* bp = (unsigned*)ws;                     // 512 KB bf16 points
    float* sq = (float*)(ws + 524288);                // 32 KB norms
    unsigned* cnt = (unsigned*)(ws + 524288 + 32768); // 16 KB global hist
    double* sums = (double*)(ws + 524288 + 32768 + 16384);

    hipMemsetAsync(cnt, 0, NBINS * sizeof(unsigned), stream);
    hipMemsetAsync(sums, 0, (NR + 1) * sizeof(double), stream);
    k_prep<<<64, 256, 0, stream>>>(pts, bp, sq);
    k_hist<<<NBLK, 256, 0, stream>>>((const uint4*)bp, sq, cnt);
    k_sig<<<NBINS / 256, 256, 0, stream>>>(cnt, rv, sums);
    k_fit<<<1, 1, 0, stream>>>(sums, rv, out);
}

// Round 9
// 60.422 us; speedup vs baseline: 15.7198x; 1.1515x over previous
//
#include <hip/hip_runtime.h>
#include <math.h>

#define NPTS 8192
#define DIM 32
#define TILE 128
#define NT (NPTS / TILE)              // 64 tiles per side
#define NTP (NT * (NT + 1) / 2)       // 2080 upper-tri tile pairs
#define NBINS 4096
#define BIN_SCALE 20.0f               // bins per unit d^2
#define NR 16
#define NBLK 512                      // k_hist persistent grid
#define LROW 40                       // shorts per LDS panel row (80 B padded)

using bf16x8 = __attribute__((ext_vector_type(8))) short;
using f32x4  = __attribute__((ext_vector_type(4))) float;

__device__ __forceinline__ unsigned short f2bf(float f) {
    unsigned u = __float_as_uint(f);
    return (unsigned short)((u + 0x7fffu + ((u >> 16) & 1u)) >> 16);
}

// ---------------- kernel 0: fp32 -> bf16 + exact norms + zero cnt ----------
__global__ void k_prep(const float* __restrict__ pts, unsigned* __restrict__ bp,
                       float* __restrict__ sq, unsigned* __restrict__ cnt) {
    const int t = blockIdx.x * 256 + threadIdx.x;   // 0..16383
    if (t < NBINS) cnt[t] = 0u;                     // replaces hipMemsetAsync
    const int p = t >> 1, h = t & 1;
    const float4* src = (const float4*)(pts + (size_t)p * DIM + h * 16);
    const float4 v0 = src[0], v1 = src[1], v2 = src[2], v3 = src[3];
    float s = v0.x * v0.x + v0.y * v0.y + v0.z * v0.z + v0.w * v0.w
            + v1.x * v1.x + v1.y * v1.y + v1.z * v1.z + v1.w * v1.w
            + v2.x * v2.x + v2.y * v2.y + v2.z * v2.z + v2.w * v2.w
            + v3.x * v3.x + v3.y * v3.y + v3.z * v3.z + v3.w * v3.w;
    s += __shfl_xor(s, 1);
    if (!h) sq[p] = s;
    unsigned* dst = bp + (size_t)p * 16 + h * 8;    // 8 uints = 16 bf16
    dst[0] = (unsigned)f2bf(v0.x) | ((unsigned)f2bf(v0.y) << 16);
    dst[1] = (unsigned)f2bf(v0.z) | ((unsigned)f2bf(v0.w) << 16);
    dst[2] = (unsigned)f2bf(v1.x) | ((unsigned)f2bf(v1.y) << 16);
    dst[3] = (unsigned)f2bf(v1.z) | ((unsigned)f2bf(v1.w) << 16);
    dst[4] = (unsigned)f2bf(v2.x) | ((unsigned)f2bf(v2.y) << 16);
    dst[5] = (unsigned)f2bf(v2.z) | ((unsigned)f2bf(v2.w) << 16);
    dst[6] = (unsigned)f2bf(v3.x) | ((unsigned)f2bf(v3.y) << 16);
    dst[7] = (unsigned)f2bf(v3.z) | ((unsigned)f2bf(v3.w) << 16);
}

// ---------------- kernel 1: MFMA gram + d^2 histogram ----------------------
// DIM=32 == K of mfma_f32_16x16x32_bf16: one MFMA = one full 16x16 gram
// block; acc (4 VGPRs) consumed immediately -> nothing to spill.
// Diag/off-diag split: DIAGQ is a compile-time 0/1; off-diag tiles fold the
// per-pair predicate away. r8 bug: predicate must use EACH element's row
// (GROW), not element 0's -- fixed by passing GROW into the macro condition.

#define EPI1(ACC, SA, GROW, DIAGQ) { \
    const float d2_ = fmaf(-2.f, ACC, (SA) + sb); \
    const int bin_ = (int)fminf(fmaxf(d2_, 0.f) * BIN_SCALE, (float)(NBINS - 1)); \
    if (!(DIAGQ) || ((GROW) < gcol)) atomicAdd(&hist[bin_], 1u); }

#define TCLOOP(DIAGQ) \
    _Pragma("unroll") \
    for (int tc = 0; tc < 8; ++tc) { \
        const bf16x8 bf = *(const bf16x8*)&Bb[(tc * 16 + l15) * LROW + lc * 8]; \
        const f32x4 z = {0.f, 0.f, 0.f, 0.f}; \
        const f32x4 d0 = __builtin_amdgcn_mfma_f32_16x16x32_bf16(a0, bf, z, 0, 0, 0); \
        const f32x4 d1 = __builtin_amdgcn_mfma_f32_16x16x32_bf16(a1, bf, z, 0, 0, 0); \
        const float sb = sqb[tc * 16 + l15]; \
        const int gcol = tj * TILE + tc * 16 + l15; (void)gcol; \
        EPI1(d0[0], sa00, g0 + 0, DIAGQ) EPI1(d0[1], sa01, g0 + 1, DIAGQ) \
        EPI1(d0[2], sa02, g0 + 2, DIAGQ) EPI1(d0[3], sa03, g0 + 3, DIAGQ) \
        EPI1(d1[0], sa10, g1 + 0, DIAGQ) EPI1(d1[1], sa11, g1 + 1, DIAGQ) \
        EPI1(d1[2], sa12, g1 + 2, DIAGQ) EPI1(d1[3], sa13, g1 + 3, DIAGQ) \
    }

__global__ __launch_bounds__(256)
void k_hist(const uint4* __restrict__ bp4, const float* __restrict__ sq,
            unsigned* __restrict__ cnt) {
    __shared__ unsigned hist[NBINS];                 // 16 KB
    __shared__ unsigned short Ab[TILE * LROW];       // 10 KB
    __shared__ unsigned short Bb[TILE * LROW];       // 10 KB
    __shared__ float sqa[TILE], sqb[TILE];           // 1 KB
    const int tid = threadIdx.x;
    const int lane = tid & 63, w = tid >> 6;
    const int l15 = lane & 15, lc = lane >> 4;       // col-in-tile, k-chunk
    for (int b = tid; b < NBINS; b += 256) hist[b] = 0u;
    const int P = gridDim.x;

    for (int tp = blockIdx.x; tp < NTP; tp += P) {
        int ti = 0, rr = tp;
        while (rr >= NT - ti) { rr -= NT - ti; ++ti; }
        const int tj = ti + rr;

        __syncthreads();   // prior iteration's reads + atomics done
#pragma unroll
        for (int q = 0; q < 2; ++q) {
            const int g = tid + q * 256;             // 0..511
            const int p = g >> 2, c = g & 3;
            *(uint4*)&Ab[p * LROW + c * 8] = bp4[(size_t)ti * 512 + g];
            *(uint4*)&Bb[p * LROW + c * 8] = bp4[(size_t)tj * 512 + g];
        }
        if (tid < TILE) sqa[tid] = sq[ti * TILE + tid];
        else if (tid < 2 * TILE) sqb[tid - TILE] = sq[tj * TILE + (tid - TILE)];
        __syncthreads();

        const int r0 = (2 * w) * 16, r1 = r0 + 16;   // this wave's tile-rows
        const bf16x8 a0 = *(const bf16x8*)&Ab[(r0 + l15) * LROW + lc * 8];
        const bf16x8 a1 = *(const bf16x8*)&Ab[(r1 + l15) * LROW + lc * 8];
        const float sa00 = sqa[r0 + lc * 4 + 0];
        const float sa01 = sqa[r0 + lc * 4 + 1];
        const float sa02 = sqa[r0 + lc * 4 + 2];
        const float sa03 = sqa[r0 + lc * 4 + 3];
        const float sa10 = sqa[r1 + lc * 4 + 0];
        const float sa11 = sqa[r1 + lc * 4 + 1];
        const float sa12 = sqa[r1 + lc * 4 + 2];
        const float sa13 = sqa[r1 + lc * 4 + 3];
        const int g0 = ti * TILE + r0 + lc * 4;      // + j  = global row
        const int g1 = ti * TILE + r1 + lc * 4;

        if (ti != tj) {
            TCLOOP(0)
        } else {
            TCLOOP(1)
        }
    }

    __syncthreads();
    for (int b = tid; b < NBINS; b += 256) {
        const unsigned h = hist[b];
        if (h) atomicAdd(&cnt[b], h);                // device-scope, deterministic
    }
}

// ---------------- kernel 2: sigmoid sums + regression (single block) ------
__global__ __launch_bounds__(1024)
void k_final(const unsigned* __restrict__ cnt, const float* __restrict__ rvals,
             float* __restrict__ out) {
    __shared__ double red[16][NR + 1];               // per-wave partials
    const int tid = threadIdx.x;
    float rv[NR];
#pragma unroll
    for (int t = 0; t < NR; ++t) rv[t] = rvals[t];

    double local[NR + 1];
#pragma unroll
    for (int t = 0; t <= NR; ++t) local[t] = 0.0;

#pragma unroll
    for (int q = 0; q < NBINS / 1024; ++q) {
        const int b = tid + q * 1024;
        const unsigned c = cnt[b];
        if (c) {
            const double cd = (double)c;
            local[NR] += cd;
            const float d = sqrtf(((float)b + 0.5f) / BIN_SCALE);
#pragma unroll
            for (int t = 0; t < NR; ++t) {
                const float x = 10.0f * (rv[t] - d);
                float s;
                if (x >= 0.f) s = 1.f / (1.f + __expf(-x));
                else          { const float e = __expf(x); s = e / (1.f + e); }
                local[t] += cd * (double)s;
            }
        }
    }

#pragma unroll
    for (int off = 32; off > 0; off >>= 1) {
#pragma unroll
        for (int t = 0; t <= NR; ++t)
            local[t] += __shfl_down(local[t], off);
    }
    const int wv = tid >> 6;
    if ((tid & 63) == 0) {
#pragma unroll
        for (int t = 0; t <= NR; ++t) red[wv][t] = local[t];
    }
    __syncthreads();

    if (tid == 0) {
        double sums[NR + 1];
#pragma unroll
        for (int t = 0; t <= NR; ++t) {
            double s = 0.0;
#pragma unroll
            for (int w2 = 0; w2 < 16; ++w2) s += red[w2][t];
            sums[t] = s;
        }
        const double cdn = sums[NR];
        double Sx = 0, Sy = 0, Sxx = 0, Sxy = 0;
#pragma unroll
        for (int t = 0; t < NR; ++t) {
            const double x = log((double)rv[t]);
            const double y = log(sums[t] / cdn);
            Sx += x; Sy += y; Sxx += x * x; Sxy += x * y;
        }
        const double R = (double)NR;
        const double slope = (R * Sxy - Sx * Sy) / (R * Sxx - Sx * Sx);
        out[0] = (float)(-slope);
    }
}

extern "C" void kernel_launch(void* const* d_in, const int* in_sizes, int n_in,
                              void* d_out, int out_size, void* d_ws, size_t ws_size,
                              hipStream_t stream) {
    const float* pts = (const float*)d_in[0];
    const float* rv  = (const float*)d_in[1];
    float* out = (float*)d_out;
    char* ws = (char*)d_ws;

    unsigned* bp = (unsigned*)ws;                     // 512 KB bf16 points
    float* sq = (float*)(ws + 524288);                // 32 KB norms
    unsigned* cnt = (unsigned*)(ws + 524288 + 32768); // 16 KB global hist

    k_prep<<<64, 256, 0, stream>>>(pts, bp, sq, cnt);
    k_hist<<<NBLK, 256, 0, stream>>>((const uint4*)bp, sq, cnt);
    k_final<<<1, 1024, 0, stream>>>(cnt, rv, out);
}